// Round 2
// baseline (379.528 us; speedup 1.0000x reference)
//
#include <hip/hip_runtime.h>
#include <stdint.h>

// out[b,c] = sum_{k<256} batchs[b,k] * label2embed[c,k]
// A = batchs [16384, 256] fp32 row-major, Bm = label2embed [4096, 256] fp32 row-major
// out [16384, 4096] fp32. GEMM-BT, K=256. Output-write-bound: floor ~45 us (268 MB @ 6.2 TB/s).
//
// Round-1 findings: the harness's 1 GiB workspace poison-fill (~166 us) is UNCONDITIONAL
// and inside the timed region -> using d_ws is free. Fusing cvt into the GEMM was a 50x
// VALU-work blowup (per-block conversion) -> two-pass is right.
// Round-2 theory: inputs are L2-resident (A 8MB + B 2MB bf16; 3MB/XCD with banding) and
// each fragment is read <=2x per block -> LDS staging saves ~nothing but costs the
// barrier+vmcnt-drain pipeline with only 8 K-steps to amortize. Drop LDS entirely:
// MFMA fragments load straight from global (L2), zero barriers, full-K unroll,
// 16 waves/CU for latency hiding.
#define MDIM 16384
#define NDIM 4096
#define KDIM 256

#define BM 128
#define BN 128

typedef __attribute__((ext_vector_type(8))) short bf16x8;
typedef __attribute__((ext_vector_type(4))) float f32x4;

__device__ __forceinline__ unsigned short f2bf_rne(float f) {
    union { float f; uint32_t u; } v; v.f = f;
    uint32_t u = v.u;
    u += 0x7fffu + ((u >> 16) & 1u);   // round-to-nearest-even (finite inputs)
    return (unsigned short)(u >> 16);
}

// Pass 1: fp32 -> bf16 for both inputs, into workspace. 8 elems/thread, 16B stores.
// Total traffic: 21 MB read + 10.5 MB write -> ~6 us.
__global__ __launch_bounds__(256) void cvt_kernel(const float* __restrict__ a,
                                                  const float* __restrict__ b,
                                                  unsigned short* __restrict__ wa,
                                                  unsigned short* __restrict__ wb) {
    const int64_t nA = (int64_t)MDIM * KDIM;
    int64_t i = ((int64_t)blockIdx.x * 256 + threadIdx.x) * 8;
    const float* src; unsigned short* dst; int64_t off;
    if (i < nA) { src = a; dst = wa; off = i; }
    else        { src = b; dst = wb; off = i - nA; }
    float4 f0 = *(const float4*)(src + off);
    float4 f1 = *(const float4*)(src + off + 4);
    union { unsigned short h[8]; int4 v; } o;
    o.h[0] = f2bf_rne(f0.x); o.h[1] = f2bf_rne(f0.y);
    o.h[2] = f2bf_rne(f0.z); o.h[3] = f2bf_rne(f0.w);
    o.h[4] = f2bf_rne(f1.x); o.h[5] = f2bf_rne(f1.y);
    o.h[6] = f2bf_rne(f1.z); o.h[7] = f2bf_rne(f1.w);
    *(int4*)(dst + off) = o.v;
}

// Pass 2: LDS-free bf16 MFMA GEMM-BT. 128x128 tile/block, 4 waves, each wave a 64x64
// quadrant = 4x4 MFMA 16x16 tiles. Fragments loaded DIRECTLY from global (L2-resident):
// af[i]: lane reads 16B at row(bm,wm,i,r16)*512B + k-offset -> per wave, 16 rows x 64B
// contiguous segments (quad covers 4x16B). No __syncthreads, no LDS, no staging VALU.
// Full K unroll (8 steps x 16 MFMA) lets the compiler hoist loads across steps.
// __launch_bounds__(256,4): VGPR<=128, no LDS -> 4 blocks/CU = 16 waves/CU of TLP.
__global__ __launch_bounds__(256, 4) void gemm_direct(const unsigned short* __restrict__ A,
                                                      const unsigned short* __restrict__ Bm,
                                                      float* __restrict__ out) {
    const int tid  = threadIdx.x;
    const int lane = tid & 63;
    const int wave = tid >> 6;
    const int wm   = wave >> 1;
    const int wn   = wave & 1;
    const int quad = lane >> 4;
    const int r16  = lane & 15;

    // XCD-aware swizzle: xcd = blockIdx % 8 (round-robin dispatch). Each XCD owns a
    // private band of 16 bm's; bn sweeps fastest -> per-XCD working set = A band (1 MB)
    // + full B (2 MB) = 3 MB, fits the 4 MB XCD L2. 4096 blocks, nwg%8==0 -> bijective.
    const int id  = blockIdx.x;
    const int xcd = id & 7;
    const int g   = id >> 3;                // 0..511
    const int bm  = (xcd << 4) | (g >> 5);  // 0..127
    const int bn  = g & 31;                 // 0..31

    // Per-lane fragment base: row chosen by r16, k-slice by quad (16B granules).
    const unsigned short* Ab = A  + (size_t)(bm * BM + wm * 64 + r16) * KDIM + quad * 8;
    const unsigned short* Bb = Bm + (size_t)(bn * BN + wn * 64 + r16) * KDIM + quad * 8;

    f32x4 acc[4][4] = {};

#pragma unroll
    for (int s = 0; s < KDIM / 32; ++s) {       // 8 K-steps of 32
        bf16x8 af[4], bfr[4];
#pragma unroll
        for (int i = 0; i < 4; ++i)
            af[i] = *(const bf16x8*)(Ab + (size_t)i * 16 * KDIM + s * 32);
#pragma unroll
        for (int j = 0; j < 4; ++j)
            bfr[j] = *(const bf16x8*)(Bb + (size_t)j * 16 * KDIM + s * 32);

        // SWAPPED operands (verified round 1): D = mfma(bfr, af) ->
        // D-col (lane&15) = A-row field, D-row (quad*4+reg) = B-row field.
        // Lane then holds out[Arow(i,r16)][Bcol(j) + quad*4 .. +3] -> float4 stores.
#pragma unroll
        for (int i = 0; i < 4; ++i)
#pragma unroll
            for (int j = 0; j < 4; ++j)
                acc[i][j] = __builtin_amdgcn_mfma_f32_16x16x32_bf16(bfr[j], af[i], acc[i][j], 0, 0, 0);
    }

    // Epilogue: per lane, f32x4 at 4 consecutive cols; per instruction 16 rows x 64B
    // contiguous. Nontemporal: output is a 268 MB write-once stream.
#pragma unroll
    for (int i = 0; i < 4; ++i) {
        size_t row = (size_t)bm * BM + wm * 64 + i * 16 + r16;
#pragma unroll
        for (int j = 0; j < 4; ++j) {
            int col = bn * BN + wn * 64 + j * 16 + quad * 4;
            __builtin_nontemporal_store(acc[i][j], (f32x4*)(out + row * NDIM + col));
        }
    }
}

// Fallback (only if ws too small): fp32 dot, one thread per output.
__global__ __launch_bounds__(256) void naive_f32(const float* __restrict__ a,
                                                 const float* __restrict__ b,
                                                 float* __restrict__ out) {
    int64_t idx = (int64_t)blockIdx.x * 256 + threadIdx.x;
    int c = (int)(idx & (NDIM - 1));
    int r = (int)(idx >> 12);
    const float4* ap = (const float4*)(a + (size_t)r * KDIM);
    const float4* bp = (const float4*)(b + (size_t)c * KDIM);
    float s = 0.f;
#pragma unroll 8
    for (int k = 0; k < KDIM / 4; ++k) {
        float4 x = ap[k], y = bp[k];
        s += x.x * y.x + x.y * y.y + x.z * y.z + x.w * y.w;
    }
    out[idx] = s;
}

extern "C" void kernel_launch(void* const* d_in, const int* in_sizes, int n_in,
                              void* d_out, int out_size, void* d_ws, size_t ws_size,
                              hipStream_t stream) {
    const float* a = (const float*)d_in[0];   // batchs  [16384, 2, 128]
    const float* b = (const float*)d_in[1];   // label2embed [4096, 2, 128]
    float* out = (float*)d_out;               // [16384, 4096]

    const size_t need = ((size_t)MDIM + NDIM) * KDIM * sizeof(unsigned short); // 10.5 MB
    if (d_ws != nullptr && ws_size >= need) {
        unsigned short* wa = (unsigned short*)d_ws;
        unsigned short* wb = wa + (size_t)MDIM * KDIM;
        const int64_t nvec = ((int64_t)MDIM + NDIM) * KDIM / 8;  // 655,360
        cvt_kernel<<<(int)(nvec / 256), 256, 0, stream>>>(a, b, wa, wb);          // 2560 blocks
        gemm_direct<<<(MDIM / BM) * (NDIM / BN), 256, 0, stream>>>(wa, wb, out);  // 4096 blocks
    } else {
        naive_f32<<<(int64_t)MDIM * NDIM / 256, 256, 0, stream>>>(a, b, out);
    }
}

// Round 3
// 297.541 us; speedup vs baseline: 1.2756x; 1.2756x over previous
//
#include <hip/hip_runtime.h>
#include <stdint.h>

// out[b,c] = sum_{k<256} batchs[b,k] * label2embed[c,k]
// A = batchs [16384, 256] fp32 row-major, Bm = label2embed [4096, 256] fp32 row-major
// out [16384, 4096] fp32. GEMM-BT, K=256. Output-write floor: 43.7 us (268 MB @ 6.3 TB/s).
//
// Session ledger:
//  R0: fill(~170, unconditional harness poison) + cvt(6) + gemm_bt(117, LDS dbuf, scalar
//      store epilogue) = 297 us.
//  R1: fused cvt into gemm = 50x VALU cvt blowup -> gemm 186 us. REVERTED.
//  R2: no-LDS direct-from-L2 fragments -> gemm 206 us (2x L2 traffic, scattered 16-segment
//      loads, VALU addr arith). REVERTED. global_load_lds staging is the fast path.
//  R3 (this): R0 structure EXACTLY, one change: swapped-operand MFMA -> lane holds 4
//      consecutive out cols -> epilogue 16 dwordx4 stores/lane instead of 64 dword.
//      gemm is ~2.7x the write floor; betting the store path is the limiter.
#define MDIM 16384
#define NDIM 4096
#define KDIM 256

#define BM 128
#define BN 128
#define BK 32
#define KSTEPS (KDIM / BK)   // 8

typedef __attribute__((ext_vector_type(8))) short bf16x8;
typedef __attribute__((ext_vector_type(4))) float f32x4;

__device__ __forceinline__ unsigned short f2bf_rne(float f) {
    union { float f; uint32_t u; } v; v.f = f;
    uint32_t u = v.u;
    u += 0x7fffu + ((u >> 16) & 1u);   // round-to-nearest-even (finite inputs)
    return (unsigned short)(u >> 16);
}

// Pass 1: fp32 -> bf16 for both inputs, into workspace. 8 elems/thread, 16B stores.
// Total traffic: 21 MB read + 10.5 MB write -> ~6 us.
__global__ __launch_bounds__(256) void cvt_kernel(const float* __restrict__ a,
                                                  const float* __restrict__ b,
                                                  unsigned short* __restrict__ wa,
                                                  unsigned short* __restrict__ wb) {
    const int64_t nA = (int64_t)MDIM * KDIM;
    int64_t i = ((int64_t)blockIdx.x * 256 + threadIdx.x) * 8;
    const float* src; unsigned short* dst; int64_t off;
    if (i < nA) { src = a; dst = wa; off = i; }
    else        { src = b; dst = wb; off = i - nA; }
    float4 f0 = *(const float4*)(src + off);
    float4 f1 = *(const float4*)(src + off + 4);
    union { unsigned short h[8]; int4 v; } o;
    o.h[0] = f2bf_rne(f0.x); o.h[1] = f2bf_rne(f0.y);
    o.h[2] = f2bf_rne(f0.z); o.h[3] = f2bf_rne(f0.w);
    o.h[4] = f2bf_rne(f1.x); o.h[5] = f2bf_rne(f1.y);
    o.h[6] = f2bf_rne(f1.z); o.h[7] = f2bf_rne(f1.w);
    *(int4*)(dst + off) = o.v;
}

// Stage one 128x32 bf16 tile of A and B into LDS via width-16 global_load_lds.
// chunk ch in [0,512): row = ch>>2, col = (ch&3)*8; LDS byte off = ch*16
// -> per-wave uniform base + lane*16 (matches global_load_lds HW placement).
__device__ __forceinline__ void stage_tiles(const unsigned short* __restrict__ Ab,
                                            const unsigned short* __restrict__ Bb,
                                            unsigned short* sA, unsigned short* sB,
                                            int tid, int k0) {
#pragma unroll
    for (int c = 0; c < 2; ++c) {
        int ch  = tid + c * 256;
        int row = ch >> 2;
        int col = (ch & 3) << 3;
        __builtin_amdgcn_global_load_lds(
            (const __attribute__((address_space(1))) void*)(Ab + (size_t)row * KDIM + k0 + col),
            (__attribute__((address_space(3))) void*)(sA + ch * 8), 16, 0, 0);
        __builtin_amdgcn_global_load_lds(
            (const __attribute__((address_space(1))) void*)(Bb + (size_t)row * KDIM + k0 + col),
            (__attribute__((address_space(3))) void*)(sB + ch * 8), 16, 0, 0);
    }
}

// Pass 2: bf16 MFMA GEMM-BT. 128x128 tile/block, 256 thr = 4 waves, each wave a
// 64x64 quadrant = 4x4 MFMA 16x16 tiles. BK=32, 8 K-steps, DOUBLE-BUFFERED LDS:
// one barrier per step; loads for step k+1 issued right after the barrier so the
// next barrier's vmcnt(0) drain overlaps the whole compute phase of step k.
// __launch_bounds__(256,4): cap VGPR<=128 -> 16 waves/CU (4 blocks/CU).
__global__ __launch_bounds__(256, 4) void gemm_bt(const unsigned short* __restrict__ A,
                                                  const unsigned short* __restrict__ Bm,
                                                  float* __restrict__ out) {
    __shared__ __align__(16) unsigned short sA[2][BM * BK];  // 2 x 8 KiB
    __shared__ __align__(16) unsigned short sB[2][BN * BK];  // 2 x 8 KiB

    const int tid  = threadIdx.x;
    const int lane = tid & 63;
    const int wave = tid >> 6;
    const int wm   = wave >> 1;
    const int wn   = wave & 1;
    const int quad = lane >> 4;
    const int r16  = lane & 15;

    // XCD-aware swizzle: xcd = blockIdx % 8 (round-robin dispatch). Each XCD owns a
    // private band of 16 bm's; bn sweeps fastest -> per-XCD working set = A band (1 MB)
    // + full B (2 MB) = 3 MB, fits the 4 MB XCD L2. 4096 blocks, nwg%8==0 -> bijective.
    const int id  = blockIdx.x;
    const int xcd = id & 7;
    const int g   = id >> 3;                // 0..511
    const int bm  = (xcd << 4) | (g >> 5);  // 0..127
    const int bn  = g & 31;                 // 0..31

    const unsigned short* Ab = A  + (size_t)bm * BM * KDIM;
    const unsigned short* Bb = Bm + (size_t)bn * BN * KDIM;

    f32x4 acc[4][4] = {};

    stage_tiles(Ab, Bb, sA[0], sB[0], tid, 0);

#pragma unroll
    for (int step = 0; step < KSTEPS; ++step) {
        __syncthreads();  // drains vmcnt for buf[step&1]; WAR-protects buf[(step+1)&1]
        if (step + 1 < KSTEPS)
            stage_tiles(Ab, Bb, sA[(step + 1) & 1], sB[(step + 1) & 1], tid, (step + 1) * BK);

        const unsigned short* cA = sA[step & 1];
        const unsigned short* cB = sB[step & 1];

        // Fragment: X[row = lane&15][k = quad*8 + j]  (one ds_read_b128 each)
        bf16x8 af[4], bfr[4];
#pragma unroll
        for (int i = 0; i < 4; ++i)
            af[i] = *(const bf16x8*)(cA + ((wm * 64 + i * 16 + r16) * BK + quad * 8));
#pragma unroll
        for (int j = 0; j < 4; ++j)
            bfr[j] = *(const bf16x8*)(cB + ((wn * 64 + j * 16 + r16) * BK + quad * 8));

        // SWAPPED operands (correctness validated R1/R2): D = mfma(bfr, af) ->
        // D col-field (lane&15) = A-row (out row), D row-field (quad*4+reg) = B-row
        // (out col). Lane then holds out[row][col..col+3] -> f32x4 stores.
#pragma unroll
        for (int i = 0; i < 4; ++i)
#pragma unroll
            for (int j = 0; j < 4; ++j)
                acc[i][j] = __builtin_amdgcn_mfma_f32_16x16x32_bf16(bfr[j], af[i], acc[i][j], 0, 0, 0);
    }

    // Epilogue: 16 dwordx4 stores/lane (was 64 dword). Per instruction: 16 rows x 64B.
    // PLAIN stores (not nontemporal): let L2 write-combine 64B halves into full lines;
    // R0 baseline used plain stores, keeping store width the only changed variable.
#pragma unroll
    for (int i = 0; i < 4; ++i) {
        size_t row = (size_t)bm * BM + wm * 64 + i * 16 + r16;
#pragma unroll
        for (int j = 0; j < 4; ++j) {
            int col = bn * BN + wn * 64 + j * 16 + quad * 4;
            *(f32x4*)(out + row * NDIM + col) = acc[i][j];
        }
    }
}

// Fallback (only if ws too small): fp32 dot, one thread per output.
__global__ __launch_bounds__(256) void naive_f32(const float* __restrict__ a,
                                                 const float* __restrict__ b,
                                                 float* __restrict__ out) {
    int64_t idx = (int64_t)blockIdx.x * 256 + threadIdx.x;
    int c = (int)(idx & (NDIM - 1));
    int r = (int)(idx >> 12);
    const float4* ap = (const float4*)(a + (size_t)r * KDIM);
    const float4* bp = (const float4*)(b + (size_t)c * KDIM);
    float s = 0.f;
#pragma unroll 8
    for (int k = 0; k < KDIM / 4; ++k) {
        float4 x = ap[k], y = bp[k];
        s += x.x * y.x + x.y * y.y + x.z * y.z + x.w * y.w;
    }
    out[idx] = s;
}

extern "C" void kernel_launch(void* const* d_in, const int* in_sizes, int n_in,
                              void* d_out, int out_size, void* d_ws, size_t ws_size,
                              hipStream_t stream) {
    const float* a = (const float*)d_in[0];   // batchs  [16384, 2, 128]
    const float* b = (const float*)d_in[1];   // label2embed [4096, 2, 128]
    float* out = (float*)d_out;               // [16384, 4096]

    const size_t need = ((size_t)MDIM + NDIM) * KDIM * sizeof(unsigned short); // 10.5 MB
    if (d_ws != nullptr && ws_size >= need) {
        unsigned short* wa = (unsigned short*)d_ws;
        unsigned short* wb = wa + (size_t)MDIM * KDIM;
        const int64_t nvec = ((int64_t)MDIM + NDIM) * KDIM / 8;  // 655,360
        cvt_kernel<<<(int)(nvec / 256), 256, 0, stream>>>(a, b, wa, wb);       // 2560 blocks
        gemm_bt<<<(MDIM / BM) * (NDIM / BN), 256, 0, stream>>>(wa, wb, out);   // 4096 blocks
    } else {
        naive_f32<<<(int64_t)MDIM * NDIM / 256, 256, 0, stream>>>(a, b, out);
    }
}